// Round 1
// baseline (195.301 us; speedup 1.0000x reference)
//
#include <hip/hip_runtime.h>
#include <hip/hip_bf16.h>
#include <stdint.h>

typedef unsigned short u16;
typedef __bf16 bf16_t;
typedef bf16_t bf16x8 __attribute__((ext_vector_type(8)));
typedef float f32x4 __attribute__((ext_vector_type(4)));

#define NTOK 32768
#define CEMB 256
#define NHEAD 8
#define HD 32
#define BSEG 128
#define TSEG 256

static __device__ __forceinline__ bf16x8 ld16(const u16* p) {
  uint4 v = *reinterpret_cast<const uint4*>(p);
  return __builtin_bit_cast(bf16x8, v);
}
static __device__ __forceinline__ u16 f2b(float f) {
  return __builtin_bit_cast(u16, (bf16_t)f);
}

// ---------------- K0: convert x and weights to bf16 ----------------
__global__ void k_convert(const float* __restrict__ x,
                          const float* __restrict__ wq, const float* __restrict__ wk,
                          const float* __restrict__ wv, const float* __restrict__ wp,
                          u16* __restrict__ xb, u16* __restrict__ wb) {
  const int XSLOTS = (NTOK * CEMB) / 8;      // 1048576
  const int WSLOTS = (4 * CEMB * CEMB) / 8;  // 32768
  int slot = blockIdx.x * blockDim.x + threadIdx.x;
  if (slot >= XSLOTS + WSLOTS) return;
  const float* src;
  u16* dst;
  if (slot < XSLOTS) {
    src = x + slot * 8;
    dst = xb + slot * 8;
  } else {
    int e = (slot - XSLOTS) * 8;
    int wsel = e >> 16, off = e & 65535;
    const float* s0 = (wsel == 0) ? wq : ((wsel == 1) ? wk : ((wsel == 2) ? wv : wp));
    src = s0 + off;
    dst = wb + e;
  }
  float4 a = reinterpret_cast<const float4*>(src)[0];
  float4 b = reinterpret_cast<const float4*>(src)[1];
  u16 o[8] = {f2b(a.x), f2b(a.y), f2b(a.z), f2b(a.w),
              f2b(b.x), f2b(b.y), f2b(b.z), f2b(b.w)};
  *reinterpret_cast<uint4*>(dst) = *reinterpret_cast<const uint4*>(o);
}

// ---------------- K1: QKV projection GEMMs ----------------
// out[m,c] = sum_k xb[m,k]*W[c,k] + bias[c]; mode z: 0=Q,1=K,2=V(transposed store)
__global__ __launch_bounds__(256, 4)
void k_qkv(const u16* __restrict__ xb, const u16* __restrict__ wb,
           const float* __restrict__ bq, const float* __restrict__ bk,
           const float* __restrict__ bv,
           u16* __restrict__ q_ws, u16* __restrict__ k_ws, u16* __restrict__ v_ws) {
  const int mode = blockIdx.z;
  const int m0 = blockIdx.x * 128;
  const int n0 = blockIdx.y * 64;
  const int tid = threadIdx.x;
  const int w = tid >> 6, l = tid & 63;
  const int lr = l & 15, lg = l >> 4;
  __shared__ u16 Ts[64][136];  // V-transpose bounce buffer

  const u16* W = wb + mode * (CEMB * CEMB);
  const float* bias = (mode == 0) ? bq : ((mode == 1) ? bk : bv);

  f32x4 acc[2][4];
#pragma unroll
  for (int mf = 0; mf < 2; ++mf)
#pragma unroll
    for (int nf = 0; nf < 4; ++nf) {
      f32x4 z = {0.f, 0.f, 0.f, 0.f};
      acc[mf][nf] = z;
    }
  const int mrow = m0 + w * 32;

#pragma unroll
  for (int kt = 0; kt < 4; ++kt) {
    bf16x8 af[2][2];
#pragma unroll
    for (int mf = 0; mf < 2; ++mf)
#pragma unroll
      for (int kk = 0; kk < 2; ++kk)
        af[mf][kk] = ld16(xb + (mrow + mf * 16 + lr) * CEMB + kt * 64 + kk * 32 + lg * 8);
#pragma unroll
    for (int nf = 0; nf < 4; ++nf) {
#pragma unroll
      for (int kk = 0; kk < 2; ++kk) {
        bf16x8 bfrag = ld16(W + (n0 + nf * 16 + lr) * CEMB + kt * 64 + kk * 32 + lg * 8);
#pragma unroll
        for (int mf = 0; mf < 2; ++mf)
          acc[mf][nf] = __builtin_amdgcn_mfma_f32_16x16x32_bf16(af[mf][kk], bfrag, acc[mf][nf], 0, 0, 0);
      }
    }
  }

  float bb[4];
#pragma unroll
  for (int nf = 0; nf < 4; ++nf) bb[nf] = bias[n0 + nf * 16 + lr];

  if (mode < 2) {
    u16* out = (mode == 0) ? q_ws : k_ws;
#pragma unroll
    for (int mf = 0; mf < 2; ++mf)
#pragma unroll
      for (int nf = 0; nf < 4; ++nf)
#pragma unroll
        for (int r = 0; r < 4; ++r) {
          int m = mrow + mf * 16 + lg * 4 + r;
          int c = n0 + nf * 16 + lr;
          int bs = m >> 8, t = m & 255, hh = c >> 5, d = c & 31;
          out[((bs * NHEAD + hh) * TSEG + t) * HD + d] = f2b(acc[mf][nf][r] + bb[nf]);
        }
  } else {
    // stage into LDS then store V transposed: v_ws[(b*8+h)*32+d][t]
#pragma unroll
    for (int mf = 0; mf < 2; ++mf)
#pragma unroll
      for (int nf = 0; nf < 4; ++nf)
#pragma unroll
        for (int r = 0; r < 4; ++r)
          Ts[nf * 16 + lr][w * 32 + mf * 16 + lg * 4 + r] = f2b(acc[mf][nf][r] + bb[nf]);
    __syncthreads();
    int row = tid >> 2;            // 0..63 : local c
    int seg = (tid & 3) * 32;      // t offset chunk
    int c = n0 + row, hh = c >> 5, d = c & 31;
    int bs = m0 >> 8, t0 = m0 & 255;
    u16* dst = v_ws + ((bs * NHEAD + hh) * HD + d) * TSEG + t0 + seg;
#pragma unroll
    for (int j = 0; j < 4; ++j)
      reinterpret_cast<uint4*>(dst)[j] = *reinterpret_cast<const uint4*>(&Ts[row][seg + j * 8]);
  }
}

// ---------------- K2: attention per (b, half-T) ----------------
__global__ __launch_bounds__(512, 2)
void k_attn(const u16* __restrict__ q_ws, const u16* __restrict__ k_ws,
            const u16* __restrict__ v_ws,
            u16* __restrict__ y_ws, float* __restrict__ mean_out) {
  const int b = blockIdx.y;
  const int th = blockIdx.x;        // t-half: 0/1
  const int tid = threadIdx.x;
  const int w = tid >> 6, l = tid & 63;
  const int lr = l & 15, lg = l >> 4;
  const int tbase = th * 128 + w * 16;

  __shared__ u16 Pbuf[8][4096];     // per-wave 16x256 bf16, XOR-swizzled (64KB exactly)

  f32x4 macc[16];
#pragma unroll
  for (int st = 0; st < 16; ++st) {
    f32x4 z = {0.f, 0.f, 0.f, 0.f};
    macc[st] = z;
  }
  const float scale = 0.17677669529663687f;  // 1/sqrt(32)

  for (int h = 0; h < NHEAD; ++h) {
    const u16* qh = q_ws + (b * NHEAD + h) * TSEG * HD;
    const u16* kh = k_ws + (b * NHEAD + h) * TSEG * HD;
    const u16* vh = v_ws + (b * NHEAD + h) * HD * TSEG;

    // Q fragment: rows tbase+lr, k = lg*8.. (hd=32 in one MFMA k-step)
    bf16x8 aq = ld16(qh + (tbase + lr) * HD + lg * 8);

    f32x4 s[16];
#pragma unroll
    for (int st = 0; st < 16; ++st) {
      bf16x8 bk = ld16(kh + (st * 16 + lr) * HD + lg * 8);
      f32x4 z = {0.f, 0.f, 0.f, 0.f};
      s[st] = __builtin_amdgcn_mfma_f32_16x16x32_bf16(aq, bk, z, 0, 0, 0);
    }

    // softmax over s (256) per t-row; D layout: col=s (lr), row=t (lg*4+r)
    float mx[4] = {-1e30f, -1e30f, -1e30f, -1e30f};
#pragma unroll
    for (int st = 0; st < 16; ++st)
#pragma unroll
      for (int r = 0; r < 4; ++r) {
        float v = s[st][r] * scale;
        s[st][r] = v;
        mx[r] = fmaxf(mx[r], v);
      }
#pragma unroll
    for (int off = 1; off < 16; off <<= 1)
#pragma unroll
      for (int r = 0; r < 4; ++r) mx[r] = fmaxf(mx[r], __shfl_xor(mx[r], off, 64));
    float sm[4] = {0.f, 0.f, 0.f, 0.f};
#pragma unroll
    for (int st = 0; st < 16; ++st)
#pragma unroll
      for (int r = 0; r < 4; ++r) {
        float p = __expf(s[st][r] - mx[r]);
        s[st][r] = p;
        sm[r] += p;
      }
#pragma unroll
    for (int off = 1; off < 16; off <<= 1)
#pragma unroll
      for (int r = 0; r < 4; ++r) sm[r] += __shfl_xor(sm[r], off, 64);
    float inv[4];
#pragma unroll
    for (int r = 0; r < 4; ++r) inv[r] = 1.0f / sm[r];

    // normalize, accumulate head-mean, write P (bf16) to swizzled LDS [t][s]
#pragma unroll
    for (int st = 0; st < 16; ++st)
#pragma unroll
      for (int r = 0; r < 4; ++r) {
        float p = s[st][r] * inv[r];
        macc[st][r] += p;
        int row = lg * 4 + r, col = st * 16 + lr;
        int byte = (row * 512 + col * 2) ^ ((row & 7) << 4);
        Pbuf[w][byte >> 1] = f2b(p);
      }

    // PV: A = P[t][s] from LDS, B = V^T[d][s] from global (both contiguous 16B)
    bf16x8 pa[8];
#pragma unroll
    for (int kk = 0; kk < 8; ++kk) {
      int byte = (lr * 512 + (kk * 32 + lg * 8) * 2) ^ ((lr & 7) << 4);
      pa[kk] = *reinterpret_cast<const bf16x8*>(&Pbuf[w][byte >> 1]);
    }
#pragma unroll
    for (int dt = 0; dt < 2; ++dt) {
      f32x4 y = {0.f, 0.f, 0.f, 0.f};
#pragma unroll
      for (int kk = 0; kk < 8; ++kk) {
        bf16x8 bv = ld16(vh + (dt * 16 + lr) * TSEG + kk * 32 + lg * 8);
        y = __builtin_amdgcn_mfma_f32_16x16x32_bf16(pa[kk], bv, y, 0, 0, 0);
      }
#pragma unroll
      for (int r = 0; r < 4; ++r) {
        int t = tbase + lg * 4 + r;
        y_ws[(b * TSEG + t) * CEMB + h * HD + dt * 16 + lr] = f2b(y[r]);
      }
    }
  }

  // write head-mean attention (f32), /8
#pragma unroll
  for (int st = 0; st < 16; ++st)
#pragma unroll
    for (int r = 0; r < 4; ++r) {
      int t = tbase + lg * 4 + r;
      mean_out[(b * TSEG + t) * TSEG + st * 16 + lr] = macc[st][r] * 0.125f;
    }
}

// ---------------- K3: output projection ----------------
__global__ __launch_bounds__(256, 4)
void k_proj(const u16* __restrict__ yb, const u16* __restrict__ wb,
            const float* __restrict__ bp, float* __restrict__ out) {
  const int m0 = blockIdx.x * 128;
  const int n0 = blockIdx.y * 64;
  const int tid = threadIdx.x;
  const int w = tid >> 6, l = tid & 63;
  const int lr = l & 15, lg = l >> 4;
  const u16* W = wb + 3 * (CEMB * CEMB);

  f32x4 acc[2][4];
#pragma unroll
  for (int mf = 0; mf < 2; ++mf)
#pragma unroll
    for (int nf = 0; nf < 4; ++nf) {
      f32x4 z = {0.f, 0.f, 0.f, 0.f};
      acc[mf][nf] = z;
    }
  const int mrow = m0 + w * 32;

#pragma unroll
  for (int kt = 0; kt < 4; ++kt) {
    bf16x8 af[2][2];
#pragma unroll
    for (int mf = 0; mf < 2; ++mf)
#pragma unroll
      for (int kk = 0; kk < 2; ++kk)
        af[mf][kk] = ld16(yb + (mrow + mf * 16 + lr) * CEMB + kt * 64 + kk * 32 + lg * 8);
#pragma unroll
    for (int nf = 0; nf < 4; ++nf) {
#pragma unroll
      for (int kk = 0; kk < 2; ++kk) {
        bf16x8 bfrag = ld16(W + (n0 + nf * 16 + lr) * CEMB + kt * 64 + kk * 32 + lg * 8);
#pragma unroll
        for (int mf = 0; mf < 2; ++mf)
          acc[mf][nf] = __builtin_amdgcn_mfma_f32_16x16x32_bf16(af[mf][kk], bfrag, acc[mf][nf], 0, 0, 0);
      }
    }
  }
  float bb[4];
#pragma unroll
  for (int nf = 0; nf < 4; ++nf) bb[nf] = bp[n0 + nf * 16 + lr];
#pragma unroll
  for (int mf = 0; mf < 2; ++mf)
#pragma unroll
    for (int nf = 0; nf < 4; ++nf)
#pragma unroll
      for (int r = 0; r < 4; ++r) {
        int m = mrow + mf * 16 + lg * 4 + r;
        int c = n0 + nf * 16 + lr;
        out[m * CEMB + c] = acc[mf][nf][r] + bb[nf];
      }
}

extern "C" void kernel_launch(void* const* d_in, const int* in_sizes, int n_in,
                              void* d_out, int out_size, void* d_ws, size_t ws_size,
                              hipStream_t stream) {
  (void)in_sizes; (void)n_in; (void)out_size; (void)ws_size;
  const float* x  = (const float*)d_in[0];
  // d_in[1] = batch indices (unused: equal-length segments, B=128, T=256)
  const float* Wq = (const float*)d_in[2];
  const float* bq = (const float*)d_in[3];
  const float* Wk = (const float*)d_in[4];
  const float* bk = (const float*)d_in[5];
  const float* Wv = (const float*)d_in[6];
  const float* bv = (const float*)d_in[7];
  const float* Wp = (const float*)d_in[8];
  const float* bp = (const float*)d_in[9];
  float* out = (float*)d_out;

  char* ws = (char*)d_ws;
  u16* xb   = (u16*)(ws);                    // 16,777,216 B (reused as y_ws after k_qkv)
  u16* wb   = (u16*)(ws + 16777216);         //    524,288 B
  u16* q_ws = (u16*)(ws + 17301504);         // 16,777,216 B
  u16* k_ws = (u16*)(ws + 34078720);         // 16,777,216 B
  u16* v_ws = (u16*)(ws + 50855936);         // 16,777,216 B (transposed [b,h,hd,T])
  u16* y_ws = xb;
  float* mean_out = out + (size_t)NTOK * CEMB;

  k_convert<<<4224, 256, 0, stream>>>(x, Wq, Wk, Wv, Wp, xb, wb);
  k_qkv<<<dim3(256, 4, 3), 256, 0, stream>>>(xb, wb, bq, bk, bv, q_ws, k_ws, v_ws);
  k_attn<<<dim3(2, 128), 512, 0, stream>>>(q_ws, k_ws, v_ws, y_ws, mean_out);
  k_proj<<<dim3(256, 4), 256, 0, stream>>>(y_ws, wb, bp, out);
}